// Round 2
// baseline (185.409 us; speedup 1.0000x reference)
//
#include <hip/hip_runtime.h>

// VQ-VAE eval forward, MFMA bf16x3-split path (fp32-faithful distances).
// B=64, D=64, H=32, W=32 -> N=65536 queries dim 64; K=1024 codes.
// dist(q,c) = ||e_c||^2 - 2 <x_q, e_c>  (||x||^2 dropped: per-query constant).
// <x,e> via 6 bf16 MFMA products: x=xh+xm+xl exactly; keep hh,hm,mh,mm,hl,lh.
//
// R2: register-direct B path. R1 showed the LDS round-trip is the bottleneck:
// per-tile global_load_lds -> vmcnt(0) -> barrier lockstep added ~40us of stall
// (MfmaUtil 17%, VALU 13%, conflicts ~0). The split codebook (384 KB) is
// L2-resident and every wave reads every tile anyway, so B-fragments are now
// loaded straight from ws_split into registers: NO barriers / NO LDS in the
// main loop, 1-deep software pipeline (next cs's 6 loads + norm prefetched
// under current 24 MFMAs). MFMA order and final arithmetic bit-identical.

#define DIMS 64
#define K_CODES 1024
#define N_QUERIES 65536
#define HW 1024
#define TOTAL_ELEMS 4194304
#define PLANE 4096          // shorts per plane in a code-tile buffer
#define TILE_SHORTS 12288   // 3 * PLANE
#define TILE_BYTES 24576
#define SPLIT_OFF 16384     // byte offset of split buffer in ws
#define SPLIT_BYTES 393216  // 16 tiles * 24576 B
#define NBLK 512

typedef __attribute__((ext_vector_type(8))) short v8s;   // 8 bf16 = 4 VGPR (A/B frag)
typedef __attribute__((ext_vector_type(4))) float f32x4; // C/D frag

__device__ inline unsigned short f2bf(float x) {
    union { float f; unsigned u; } v; v.f = x;
    unsigned r = v.u + 0x7fff + ((v.u >> 16) & 1);  // RNE
    return (unsigned short)(r >> 16);
}
__device__ inline float bf2f(unsigned short h) {
    union { unsigned u; float f; } v; v.u = ((unsigned)h) << 16; return v.f;
}

// ---------------- Kernel A: norms + split planes + zero accumulators ----------------
// 4 blocks x 256 threads: one thread per code. Split layout per tile t (64 codes):
// [p (3 planes)][octet o (8)][code c (64)][8 bf16]
__global__ void vq_prep(const float* __restrict__ emb, float* __restrict__ ws_norm,
                        unsigned* __restrict__ ws_flags, float* __restrict__ ws_loss,
                        int* __restrict__ ws_cnt, unsigned short* __restrict__ ws_split) {
    int k = blockIdx.x * 256 + threadIdx.x;  // 0..1023
    const float4* row = (const float4*)(emb + k * DIMS);
    unsigned short* base = ws_split ? (ws_split + (k >> 6) * TILE_SHORTS + (k & 63) * 8)
                                    : (unsigned short*)0;
    float s = 0.f;
#pragma unroll
    for (int o = 0; o < 8; ++o) {
        float4 v0 = row[o * 2], v1 = row[o * 2 + 1];
        float xs[8] = {v0.x, v0.y, v0.z, v0.w, v1.x, v1.y, v1.z, v1.w};
        unsigned h[8], m[8], l[8];
#pragma unroll
        for (int j = 0; j < 8; ++j) {
            float x = xs[j];
            s += x * x;
            unsigned short hh = f2bf(x);  float r1 = x - bf2f(hh);
            unsigned short mh = f2bf(r1); float r2 = r1 - bf2f(mh);
            h[j] = hh; m[j] = mh; l[j] = f2bf(r2);
        }
        if (base) {
            uint4 uh = {h[0] | (h[1] << 16), h[2] | (h[3] << 16),
                        h[4] | (h[5] << 16), h[6] | (h[7] << 16)};
            uint4 um = {m[0] | (m[1] << 16), m[2] | (m[3] << 16),
                        m[4] | (m[5] << 16), m[6] | (m[7] << 16)};
            uint4 ul = {l[0] | (l[1] << 16), l[2] | (l[3] << 16),
                        l[4] | (l[5] << 16), l[6] | (l[7] << 16)};
            *(uint4*)(base + 0 * PLANE + o * 512) = uh;
            *(uint4*)(base + 1 * PLANE + o * 512) = um;
            *(uint4*)(base + 2 * PLANE + o * 512) = ul;
        }
    }
    ws_norm[k] = s;
    if (k < 32) ws_flags[k] = 0u;
    if (k == 0) { *ws_loss = 0.f; *ws_cnt = 0; }
}

#define MFMA16(A_, B_, C_) __builtin_amdgcn_mfma_f32_16x16x32_bf16(A_, B_, C_, 0, 0, 0)

// ---------------- Kernel B (direct): barrier-free main loop ----------------
// 512 blocks x 256 threads (4 waves). Block = 128 queries; wave = 32 queries
// (2 row-tiles of 16), each wave scans ALL 1024 codes in 16 tiles of 64,
// reading frag-ready B directly from global (L2-resident) into registers.
__global__ __launch_bounds__(256, 2)
void vq_main_direct(const float* __restrict__ z_e, const float* __restrict__ emb,
                    const float* __restrict__ ws_norm, unsigned* __restrict__ ws_flags,
                    float* __restrict__ ws_loss, int* __restrict__ ws_cnt,
                    const unsigned short* __restrict__ ws_split,
                    float* __restrict__ out) {
    __shared__ int      fIdx[128];
    __shared__ float    wsum[4];
    __shared__ unsigned umask[32];
    __shared__ int      lastBlk;

    const int tid  = threadIdx.x;
    const int lane = tid & 63;
    const int wid  = tid >> 6;
    const int qbase = blockIdx.x * 128;
    const int b    = qbase >> 10;          // batch index (uniform per block)
    const int hwb  = qbase & (HW - 1);

    const int col  = lane & 15;  // m (A) / n (B) within 16-tile
    const int qd   = lane >> 4;  // quad -> k-octet selector

    if (tid < 32) umask[tid] = 0u;

    // ---- Build A fragments from global (coalesced), split into 3 bf16 planes ----
    v8s afr[2][2][3];
    {
        const float* zb = z_e + b * (DIMS * HW);
#pragma unroll
        for (int rt = 0; rt < 2; ++rt) {
            int hwq = hwb + wid * 32 + rt * 16 + col;
#pragma unroll
            for (int kc = 0; kc < 2; ++kc) {
                int dbase = kc * 32 + qd * 8;
#pragma unroll
                for (int j = 0; j < 8; ++j) {
                    float x = zb[(dbase + j) * HW + hwq];
                    unsigned short h = f2bf(x);  float r1 = x - bf2f(h);
                    unsigned short m = f2bf(r1); float r2 = r1 - bf2f(m);
                    afr[rt][kc][0][j] = (short)h;
                    afr[rt][kc][1][j] = (short)m;
                    afr[rt][kc][2][j] = (short)f2bf(r2);
                }
            }
        }
    }
    __syncthreads();  // umask init visible to all waves before argmin phase

    float bestv[2][4];
    int   besti[2][4];
#pragma unroll
    for (int rt = 0; rt < 2; ++rt)
#pragma unroll
        for (int r = 0; r < 4; ++r) { bestv[rt][r] = 3.4e38f; besti[rt][r] = 0; }

    // Per-lane base into the frag-ready split buffer:
    // byte addr = t*24576 + p*8192 + kc*4096 + cs*256 + qd*1024 + col*16
    const char* bp = (const char*)ws_split + qd * 1024 + col * 16;

    v8s bE[6], bO[6];   // double-buffered B fragments (kc*3+p), all static indexing
    float nE, nO;

    auto LB = [&](int byteoff, v8s* d) {
#pragma unroll
        for (int kc = 0; kc < 2; ++kc)
#pragma unroll
            for (int p = 0; p < 3; ++p)
                d[kc * 3 + p] = *(const v8s*)(bp + byteoff + p * 8192 + kc * 4096);
    };

    auto BODY = [&](const v8s* bf, float nrm, int cbase) {
        f32x4 acc0 = {0.f, 0.f, 0.f, 0.f};
        f32x4 acc1 = {0.f, 0.f, 0.f, 0.f};
#pragma unroll
        for (int kc = 0; kc < 2; ++kc) {
            acc0 = MFMA16(afr[0][kc][0], bf[kc * 3 + 0], acc0);  // hh
            acc1 = MFMA16(afr[1][kc][0], bf[kc * 3 + 0], acc1);
            acc0 = MFMA16(afr[0][kc][0], bf[kc * 3 + 1], acc0);  // hm
            acc1 = MFMA16(afr[1][kc][0], bf[kc * 3 + 1], acc1);
            acc0 = MFMA16(afr[0][kc][1], bf[kc * 3 + 0], acc0);  // mh
            acc1 = MFMA16(afr[1][kc][1], bf[kc * 3 + 0], acc1);
            acc0 = MFMA16(afr[0][kc][1], bf[kc * 3 + 1], acc0);  // mm
            acc1 = MFMA16(afr[1][kc][1], bf[kc * 3 + 1], acc1);
            acc0 = MFMA16(afr[0][kc][0], bf[kc * 3 + 2], acc0);  // hl
            acc1 = MFMA16(afr[1][kc][0], bf[kc * 3 + 2], acc1);
            acc0 = MFMA16(afr[0][kc][2], bf[kc * 3 + 0], acc0);  // lh
            acc1 = MFMA16(afr[1][kc][2], bf[kc * 3 + 0], acc1);
        }
#pragma unroll
        for (int r = 0; r < 4; ++r) {
            float d0 = fmaf(-2.f, acc0[r], nrm);
            if (d0 < bestv[0][r]) { bestv[0][r] = d0; besti[0][r] = cbase; }
            float d1 = fmaf(-2.f, acc1[r], nrm);
            if (d1 < bestv[1][r]) { bestv[1][r] = d1; besti[1][r] = cbase; }
        }
    };

    LB(0, bE);
    nE = ws_norm[col];
    for (int t = 0; t < 16; ++t) {
        const int tb  = t * TILE_BYTES;
        const int tn  = (t + 1) & 15;          // wraps at end: harmless dead prefetch
        const int tnb = tn * TILE_BYTES;
        LB(tb + 1 * 256, bO); nO = ws_norm[t * 64 + 16 + col];
        BODY(bE, nE, t * 64 + col);
        LB(tb + 2 * 256, bE); nE = ws_norm[t * 64 + 32 + col];
        BODY(bO, nO, t * 64 + 16 + col);
        LB(tb + 3 * 256, bO); nO = ws_norm[t * 64 + 48 + col];
        BODY(bE, nE, t * 64 + 32 + col);
        LB(tnb, bE);          nE = ws_norm[tn * 64 + col];
        BODY(bO, nO, t * 64 + 48 + col);
    }

    // ---- Final argmin across the 16 columns held by this quad's lanes ----
#pragma unroll
    for (int rt = 0; rt < 2; ++rt)
#pragma unroll
    for (int r = 0; r < 4; ++r) {
        float v = bestv[rt][r];
        int   idx = besti[rt][r];
#pragma unroll
        for (int m = 8; m >= 1; m >>= 1) {
            float ov = __shfl_xor(v, m, 64);
            int   oi = __shfl_xor(idx, m, 64);
            if (ov < v || (ov == v && oi < idx)) { v = ov; idx = oi; }
        }
        if (col == 0) {
            int q = wid * 32 + rt * 16 + qd * 4 + r;  // within block
            fIdx[q] = idx;
            out[TOTAL_ELEMS + 1 + qbase + q] = (float)idx;
            atomicOr(&umask[idx >> 5], 1u << (idx & 31));  // LDS, cheap
        }
    }
    __syncthreads();

    // ---- Gather z_q, write coalesced, accumulate mse partial ----
    const int q  = tid & 127;
    const int dh = tid >> 7;  // even/odd dims
    const int n  = qbase + q;
    const int bb = n >> 10;
    const int hw = n & (HW - 1);
    const int myIdx = fIdx[q];
    const float* erow = emb + myIdx * DIMS;
    float lsum = 0.f;
#pragma unroll
    for (int it = 0; it < 32; ++it) {
        int d = it * 2 + dh;
        float v = erow[d];                         // random row, L2/L3-resident
        int   o = bb * (DIMS * HW) + d * HW + hw;  // consecutive q -> coalesced
        float ze = z_e[o];
        out[o] = v;
        float df = ze - v;
        lsum = fmaf(df, df, lsum);
    }
#pragma unroll
    for (int off = 32; off > 0; off >>= 1) lsum += __shfl_down(lsum, off, 64);
    if (lane == 0) wsum[wid] = lsum;
    __syncthreads();

    // ---- Publish block results (device-scope) + last-block finalize ----
    if (tid < 32) atomicOr(&ws_flags[tid], umask[tid]);
    if (tid == 0) atomicAdd(ws_loss, wsum[0] + wsum[1] + wsum[2] + wsum[3]);
    __threadfence();  // drain this block's atomics before taking the ticket
    if (tid == 0) lastBlk = (atomicAdd(ws_cnt, 1) == NBLK - 1) ? 1 : 0;
    __syncthreads();
    if (lastBlk) {
        int c = 0;
        if (tid < 32) c = __popc(atomicOr(&ws_flags[tid], 0u));  // coherent read
        if (tid < 64) {
#pragma unroll
            for (int off = 32; off >= 1; off >>= 1) c += __shfl_down(c, off, 64);
        }
        if (tid == 0) {
            float L = atomicAdd(ws_loss, 0.f);  // coherent read
            out[TOTAL_ELEMS] = L / (float)TOTAL_ELEMS;
            out[TOTAL_ELEMS + 1 + N_QUERIES] = (float)c / (float)K_CODES;
        }
    }
}

// ---------------- Kernel B (fallback, small workspace): R0 LDS path ----------------
__global__ __launch_bounds__(256, 2)
void vq_main_lds(const float* __restrict__ z_e, const float* __restrict__ emb,
                 const float* __restrict__ ws_norm, unsigned* __restrict__ ws_flags,
                 float* __restrict__ ws_loss, int* __restrict__ ws_cnt,
                 float* __restrict__ out) {
    __shared__ unsigned short ldsB[2][3 * PLANE];  // 48 KB
    __shared__ int      fIdx[128];
    __shared__ float    wsum[4];
    __shared__ unsigned umask[32];
    __shared__ int      lastBlk;

    const int tid  = threadIdx.x;
    const int lane = tid & 63;
    const int wid  = tid >> 6;
    const int qbase = blockIdx.x * 128;
    const int b    = qbase >> 10;
    const int hwb  = qbase & (HW - 1);
    const int col  = lane & 15;
    const int qd   = lane >> 4;

    if (tid < 32) umask[tid] = 0u;

    v8s afr[2][2][3];
    {
        const float* zb = z_e + b * (DIMS * HW);
#pragma unroll
        for (int rt = 0; rt < 2; ++rt) {
            int hwq = hwb + wid * 32 + rt * 16 + col;
#pragma unroll
            for (int kc = 0; kc < 2; ++kc) {
                int dbase = kc * 32 + qd * 8;
#pragma unroll
                for (int j = 0; j < 8; ++j) {
                    float x = zb[(dbase + j) * HW + hwq];
                    unsigned short h = f2bf(x);  float r1 = x - bf2f(h);
                    unsigned short m = f2bf(r1); float r2 = r1 - bf2f(m);
                    afr[rt][kc][0][j] = (short)h;
                    afr[rt][kc][1][j] = (short)m;
                    afr[rt][kc][2][j] = (short)f2bf(r2);
                }
            }
        }
    }

    float bestv[2][4];
    int   besti[2][4];
#pragma unroll
    for (int rt = 0; rt < 2; ++rt)
#pragma unroll
        for (int r = 0; r < 4; ++r) { bestv[rt][r] = 3.4e38f; besti[rt][r] = 0; }

    float4 regs[4];
    auto stage_loads = [&](int t) {
        const float4* src = (const float4*)(emb + t * 64 * DIMS);
#pragma unroll
        for (int i = 0; i < 4; ++i) regs[i] = src[tid + 256 * i];
    };
    auto stage_write = [&](int bb2) {
        unsigned short* dst = &ldsB[bb2][0];
#pragma unroll
        for (int i = 0; i < 4; ++i) {
            int e    = (tid + 256 * i) * 4;
            int code = e >> 6;
            int d    = e & 63;
            int o    = d >> 3;
            int sub  = d & 7;
            float xs[4] = {regs[i].x, regs[i].y, regs[i].z, regs[i].w};
            unsigned short h[4], mm_[4], l[4];
#pragma unroll
            for (int q = 0; q < 4; ++q) {
                float x = xs[q];
                unsigned short hh = f2bf(x);  float r1 = x - bf2f(hh);
                unsigned short mh = f2bf(r1); float r2 = r1 - bf2f(mh);
                h[q] = hh; mm_[q] = mh; l[q] = f2bf(r2);
            }
            int base = (o * 64 + code) * 8 + sub;
            uint2 uh, um, ul;
            uh.x = (unsigned)h[0]   | ((unsigned)h[1] << 16);
            uh.y = (unsigned)h[2]   | ((unsigned)h[3] << 16);
            um.x = (unsigned)mm_[0] | ((unsigned)mm_[1] << 16);
            um.y = (unsigned)mm_[2] | ((unsigned)mm_[3] << 16);
            ul.x = (unsigned)l[0]   | ((unsigned)l[1] << 16);
            ul.y = (unsigned)l[2]   | ((unsigned)l[3] << 16);
            *(uint2*)(dst + base)             = uh;
            *(uint2*)(dst + PLANE + base)     = um;
            *(uint2*)(dst + 2 * PLANE + base) = ul;
        }
    };

    stage_loads(0);
    stage_write(0);
    __syncthreads();

    for (int t = 0; t < 16; ++t) {
        const int cur = t & 1;
        if (t < 15) stage_loads(t + 1);
        const unsigned short* bufc = &ldsB[cur][0];
#pragma unroll
        for (int cs = 0; cs < 4; ++cs) {
            float nrm = ws_norm[t * 64 + cs * 16 + col];
            v8s bfr[2][3];
#pragma unroll
            for (int kc = 0; kc < 2; ++kc)
#pragma unroll
                for (int p = 0; p < 3; ++p)
                    bfr[kc][p] = *(const v8s*)(bufc + p * PLANE +
                                 (((kc * 4 + qd) * 64) + cs * 16 + col) * 8);
            f32x4 acc0 = {0.f, 0.f, 0.f, 0.f};
            f32x4 acc1 = {0.f, 0.f, 0.f, 0.f};
#pragma unroll
            for (int kc = 0; kc < 2; ++kc) {
                acc0 = MFMA16(afr[0][kc][0], bfr[kc][0], acc0);
                acc1 = MFMA16(afr[1][kc][0], bfr[kc][0], acc1);
                acc0 = MFMA16(afr[0][kc][0], bfr[kc][1], acc0);
                acc1 = MFMA16(afr[1][kc][0], bfr[kc][1], acc1);
                acc0 = MFMA16(afr[0][kc][1], bfr[kc][0], acc0);
                acc1 = MFMA16(afr[1][kc][1], bfr[kc][0], acc1);
                acc0 = MFMA16(afr[0][kc][1], bfr[kc][1], acc0);
                acc1 = MFMA16(afr[1][kc][1], bfr[kc][1], acc1);
                acc0 = MFMA16(afr[0][kc][0], bfr[kc][2], acc0);
                acc1 = MFMA16(afr[1][kc][0], bfr[kc][2], acc1);
                acc0 = MFMA16(afr[0][kc][2], bfr[kc][0], acc0);
                acc1 = MFMA16(afr[1][kc][2], bfr[kc][0], acc1);
            }
            int cbase = t * 64 + cs * 16 + col;
#pragma unroll
            for (int r = 0; r < 4; ++r) {
                float d0 = fmaf(-2.f, acc0[r], nrm);
                if (d0 < bestv[0][r]) { bestv[0][r] = d0; besti[0][r] = cbase; }
                float d1 = fmaf(-2.f, acc1[r], nrm);
                if (d1 < bestv[1][r]) { bestv[1][r] = d1; besti[1][r] = cbase; }
            }
        }
        if (t < 15) stage_write(1 - cur);
        __syncthreads();
    }

#pragma unroll
    for (int rt = 0; rt < 2; ++rt)
#pragma unroll
    for (int r = 0; r < 4; ++r) {
        float v = bestv[rt][r];
        int   idx = besti[rt][r];
#pragma unroll
        for (int m = 8; m >= 1; m >>= 1) {
            float ov = __shfl_xor(v, m, 64);
            int   oi = __shfl_xor(idx, m, 64);
            if (ov < v || (ov == v && oi < idx)) { v = ov; idx = oi; }
        }
        if (col == 0) {
            int q = wid * 32 + rt * 16 + qd * 4 + r;
            fIdx[q] = idx;
            out[TOTAL_ELEMS + 1 + qbase + q] = (float)idx;
            atomicOr(&umask[idx >> 5], 1u << (idx & 31));
        }
    }
    __syncthreads();

    const int q  = tid & 127;
    const int dh = tid >> 7;
    const int n  = qbase + q;
    const int bb = n >> 10;
    const int hw = n & (HW - 1);
    const int myIdx = fIdx[q];
    const float* erow = emb + myIdx * DIMS;
    float lsum = 0.f;
#pragma unroll
    for (int it = 0; it < 32; ++it) {
        int d = it * 2 + dh;
        float v = erow[d];
        int   o = bb * (DIMS * HW) + d * HW + hw;
        float ze = z_e[o];
        out[o] = v;
        float df = ze - v;
        lsum = fmaf(df, df, lsum);
    }
#pragma unroll
    for (int off = 32; off > 0; off >>= 1) lsum += __shfl_down(lsum, off, 64);
    if (lane == 0) wsum[wid] = lsum;
    __syncthreads();

    if (tid < 32) atomicOr(&ws_flags[tid], umask[tid]);
    if (tid == 0) atomicAdd(ws_loss, wsum[0] + wsum[1] + wsum[2] + wsum[3]);
    __threadfence();
    if (tid == 0) lastBlk = (atomicAdd(ws_cnt, 1) == NBLK - 1) ? 1 : 0;
    __syncthreads();
    if (lastBlk) {
        int c = 0;
        if (tid < 32) c = __popc(atomicOr(&ws_flags[tid], 0u));
        if (tid < 64) {
#pragma unroll
            for (int off = 32; off >= 1; off >>= 1) c += __shfl_down(c, off, 64);
        }
        if (tid == 0) {
            float L = atomicAdd(ws_loss, 0.f);
            out[TOTAL_ELEMS] = L / (float)TOTAL_ELEMS;
            out[TOTAL_ELEMS + 1 + N_QUERIES] = (float)c / (float)K_CODES;
        }
    }
}

extern "C" void kernel_launch(void* const* d_in, const int* in_sizes, int n_in,
                              void* d_out, int out_size, void* d_ws, size_t ws_size,
                              hipStream_t stream) {
    const float* z_e = (const float*)d_in[0];
    const float* emb = (const float*)d_in[1];
    float* out = (float*)d_out;
    float*    ws_norm  = (float*)d_ws;
    unsigned* ws_flags = (unsigned*)((char*)d_ws + 4096);
    float*    ws_loss  = (float*)((char*)d_ws + 8192);
    int*      ws_cnt   = (int*)((char*)d_ws + 8256);

    bool direct = ws_size >= (size_t)(SPLIT_OFF + SPLIT_BYTES);
    unsigned short* ws_split = direct ? (unsigned short*)((char*)d_ws + SPLIT_OFF)
                                      : (unsigned short*)0;

    vq_prep<<<4, 256, 0, stream>>>(emb, ws_norm, ws_flags, ws_loss, ws_cnt, ws_split);
    if (direct)
        vq_main_direct<<<NBLK, 256, 0, stream>>>(z_e, emb, ws_norm, ws_flags, ws_loss,
                                                 ws_cnt, ws_split, out);
    else
        vq_main_lds<<<NBLK, 256, 0, stream>>>(z_e, emb, ws_norm, ws_flags, ws_loss,
                                              ws_cnt, out);
}

// Round 4
// 169.918 us; speedup vs baseline: 1.0912x; 1.0912x over previous
//
#include <hip/hip_runtime.h>

// VQ-VAE eval forward, MFMA bf16x3-split path (fp32-faithful distances).
// B=64, D=64, H=32, W=32 -> N=65536 queries dim 64; K=1024 codes.
// dist(q,c) = ||e_c||^2 - 2 <x_q, e_c>  (||x||^2 dropped: per-query constant).
// <x,e> via 6 bf16 MFMA products: x=xh+xm+xl exactly; keep hh,hm,mh,mm,hl,lh.
//
// R4 == R3 resubmitted (R3 bench was an infra failure: container died at
// acquire, no pytest/profile; kernel audited clean for OOB/race/deadlock).
// R3: back to R0's emb->LDS staging (R1/R2 proved bulk d_ws reads in the hot
// loop are a slow path: both landed ~120us with all pipes <17% busy; the only
// shared feature was ws_split traffic). Changes vs R0 (75us):
//  - 512-thr blocks, 256 queries/block (256 blocks): per-block codebook split
//    VALU amortized 2x (R0's 34% VALUBusy).
//  - LDS write-conflict fix: slot = code ^ (octet<<1) swizzle on write+read
//    (R0: 64 lanes into banks 0-15, 4-way, 1.1e7 conflict cycles).
//  - stage_write hoisted mid-tile (between cs=1 and cs=2) so split VALU and
//    ds_writes overlap MFMA at 1 block/CU (writes target the inactive buffer).
//  - vq_final fused via last-block ticket (proven in R1/R2).
// Distances/scan order bit-identical to R0 -> same indices, same absmax.

#define DIMS 64
#define K_CODES 1024
#define N_QUERIES 65536
#define HW 1024
#define TOTAL_ELEMS 4194304
#define PLANE 4096   // shorts per plane in a code-tile buffer
#define NBLK 256
#define QPB 256

typedef __attribute__((ext_vector_type(8))) short v8s;   // 8 bf16 = 4 VGPR (A/B frag)
typedef __attribute__((ext_vector_type(4))) float f32x4; // C/D frag

__device__ inline unsigned short f2bf(float x) {
    union { float f; unsigned u; } v; v.f = x;
    unsigned r = v.u + 0x7fff + ((v.u >> 16) & 1);  // RNE
    return (unsigned short)(r >> 16);
}
__device__ inline float bf2f(unsigned short h) {
    union { unsigned u; float f; } v; v.u = ((unsigned)h) << 16; return v.f;
}

// ---------------- Kernel A: code norms + zero accumulators ----------------
// Norm summation chain identical to R0 (bit-identical norms).
__global__ void vq_prep(const float* __restrict__ emb, float* __restrict__ ws_norm,
                        unsigned* __restrict__ ws_flags, float* __restrict__ ws_loss,
                        int* __restrict__ ws_cnt) {
    int k = blockIdx.x * 256 + threadIdx.x;  // 0..1023
    const float4* row = (const float4*)(emb + k * DIMS);
    float s = 0.f;
#pragma unroll
    for (int i = 0; i < 16; ++i) {
        float4 v = row[i];
        s += v.x * v.x + v.y * v.y + v.z * v.z + v.w * v.w;
    }
    ws_norm[k] = s;
    if (k < 32) ws_flags[k] = 0u;
    if (k == 0) { *ws_loss = 0.f; *ws_cnt = 0; }
}

#define MFMA16(A_, B_, C_) __builtin_amdgcn_mfma_f32_16x16x32_bf16(A_, B_, C_, 0, 0, 0)

// ---------------- Kernel B: distances + argmin + gather + loss + finalize ----------------
// 256 blocks x 512 threads (8 waves). Block = 256 queries; wave = 32 queries
// (2 row-tiles of 16), each wave scans ALL 1024 codes in 16 tiles of 64.
__global__ __launch_bounds__(512, 2)
void vq_main(const float* __restrict__ z_e, const float* __restrict__ emb,
             const float* __restrict__ ws_norm, unsigned* __restrict__ ws_flags,
             float* __restrict__ ws_loss, int* __restrict__ ws_cnt,
             float* __restrict__ out) {
    // Double-buffered code tile, frag-ready: [buf][plane p][octet o][slot][8 bf16]
    // slot = code ^ (o<<1)  (bank-conflict swizzle, bits 1-3 of code)
    __shared__ unsigned short ldsB[2][3 * PLANE];  // 48 KB
    __shared__ int      fIdx[QPB];
    __shared__ float    wsum[8];
    __shared__ unsigned umask[32];
    __shared__ int      lastBlk;

    const int tid  = threadIdx.x;
    const int lane = tid & 63;
    const int wid  = tid >> 6;             // 0..7
    const int qbase = blockIdx.x * QPB;
    const int b    = qbase >> 10;          // batch index (uniform per block)
    const int hwb  = qbase & (HW - 1);

    const int col  = lane & 15;  // m (A) / n (B) within 16-tile
    const int qd   = lane >> 4;  // quad -> k-octet selector

    if (tid < 32) umask[tid] = 0u;

    // ---- Build A fragments from global (coalesced), split into 3 bf16 planes ----
    v8s afr[2][2][3];
    {
        const float* zb = z_e + b * (DIMS * HW);
#pragma unroll
        for (int rt = 0; rt < 2; ++rt) {
            int hwq = hwb + wid * 32 + rt * 16 + col;
#pragma unroll
            for (int kc = 0; kc < 2; ++kc) {
                int dbase = kc * 32 + qd * 8;
#pragma unroll
                for (int j = 0; j < 8; ++j) {
                    float x = zb[(dbase + j) * HW + hwq];
                    unsigned short h = f2bf(x);  float r1 = x - bf2f(h);
                    unsigned short m = f2bf(r1); float r2 = r1 - bf2f(m);
                    afr[rt][kc][0][j] = (short)h;
                    afr[rt][kc][1][j] = (short)m;
                    afr[rt][kc][2][j] = (short)f2bf(r2);
                }
            }
        }
    }

    float bestv[2][4];
    int   besti[2][4];
#pragma unroll
    for (int rt = 0; rt < 2; ++rt)
#pragma unroll
        for (int r = 0; r < 4; ++r) { bestv[rt][r] = 3.4e38f; besti[rt][r] = 0; }

    // ---- Staging: tile t = 64 codes x 64 dims fp32 (16 KB), 8 floats/thread ----
    float4 regs[2];
    auto stage_loads = [&](int t) {
        const float4* src = (const float4*)(emb + t * 64 * DIMS);
#pragma unroll
        for (int i = 0; i < 2; ++i) regs[i] = src[tid + 512 * i];
    };
    // Split + scatter into frag-ready LDS layout, swizzled (8B ds_writes).
    auto stage_write = [&](int bb2) {
        unsigned short* dst = &ldsB[bb2][0];
#pragma unroll
        for (int i = 0; i < 2; ++i) {
            int e    = (tid + 512 * i) * 4;  // flat element in tile
            int code = e >> 6;
            int d    = e & 63;               // 4-aligned
            int o    = d >> 3;
            int sub  = d & 7;                // 0 or 4
            float xs[4] = {regs[i].x, regs[i].y, regs[i].z, regs[i].w};
            unsigned short h[4], mm_[4], l[4];
#pragma unroll
            for (int q = 0; q < 4; ++q) {
                float x = xs[q];
                unsigned short hh = f2bf(x);  float r1 = x - bf2f(hh);
                unsigned short mh = f2bf(r1); float r2 = r1 - bf2f(mh);
                h[q] = hh; mm_[q] = mh; l[q] = f2bf(r2);
            }
            int base = (o * 64 + (code ^ (o << 1))) * 8 + sub;  // swizzled slot
            uint2 uh, um, ul;
            uh.x = (unsigned)h[0]   | ((unsigned)h[1] << 16);
            uh.y = (unsigned)h[2]   | ((unsigned)h[3] << 16);
            um.x = (unsigned)mm_[0] | ((unsigned)mm_[1] << 16);
            um.y = (unsigned)mm_[2] | ((unsigned)mm_[3] << 16);
            ul.x = (unsigned)l[0]   | ((unsigned)l[1] << 16);
            ul.y = (unsigned)l[2]   | ((unsigned)l[3] << 16);
            *(uint2*)(dst + base)             = uh;
            *(uint2*)(dst + PLANE + base)     = um;
            *(uint2*)(dst + 2 * PLANE + base) = ul;
        }
    };

    stage_loads(0);
    stage_write(0);
    __syncthreads();

    for (int t = 0; t < 16; ++t) {
        const int cur = t & 1;
        if (t < 15) stage_loads(t + 1);
        const unsigned short* bufc = &ldsB[cur][0];

        auto csbody = [&](int cs) {
            float nrm = ws_norm[t * 64 + cs * 16 + col];
            // B-frags: B[n=col][k=qd*8+j], octet = kc*4+qd, swizzled slot.
            v8s bfr[2][3];
#pragma unroll
            for (int kc = 0; kc < 2; ++kc) {
                int oct = kc * 4 + qd;
                int slot = (cs * 16 + col) ^ (oct << 1);
#pragma unroll
                for (int p = 0; p < 3; ++p)
                    bfr[kc][p] = *(const v8s*)(bufc + p * PLANE + (oct * 64 + slot) * 8);
            }
            f32x4 acc0 = {0.f, 0.f, 0.f, 0.f};
            f32x4 acc1 = {0.f, 0.f, 0.f, 0.f};
#pragma unroll
            for (int kc = 0; kc < 2; ++kc) {
                acc0 = MFMA16(afr[0][kc][0], bfr[kc][0], acc0);  // hh
                acc1 = MFMA16(afr[1][kc][0], bfr[kc][0], acc1);
                acc0 = MFMA16(afr[0][kc][0], bfr[kc][1], acc0);  // hm
                acc1 = MFMA16(afr[1][kc][0], bfr[kc][1], acc1);
                acc0 = MFMA16(afr[0][kc][1], bfr[kc][0], acc0);  // mh
                acc1 = MFMA16(afr[1][kc][1], bfr[kc][0], acc1);
                acc0 = MFMA16(afr[0][kc][1], bfr[kc][1], acc0);  // mm
                acc1 = MFMA16(afr[1][kc][1], bfr[kc][1], acc1);
                acc0 = MFMA16(afr[0][kc][0], bfr[kc][2], acc0);  // hl
                acc1 = MFMA16(afr[1][kc][0], bfr[kc][2], acc1);
                acc0 = MFMA16(afr[0][kc][2], bfr[kc][0], acc0);  // lh
                acc1 = MFMA16(afr[1][kc][2], bfr[kc][0], acc1);
            }
            int cbase = t * 64 + cs * 16 + col;
#pragma unroll
            for (int r = 0; r < 4; ++r) {
                float d0 = fmaf(-2.f, acc0[r], nrm);
                if (d0 < bestv[0][r]) { bestv[0][r] = d0; besti[0][r] = cbase; }
                float d1 = fmaf(-2.f, acc1[r], nrm);
                if (d1 < bestv[1][r]) { bestv[1][r] = d1; besti[1][r] = cbase; }
            }
        };

        csbody(0);
        csbody(1);
        // Mid-tile stage: writes target the INACTIVE buffer (1-cur); the
        // barrier at the end of tile t-1 guarantees no wave still reads it.
        if (t < 15) stage_write(1 - cur);
        csbody(2);
        csbody(3);
        __syncthreads();
    }

    // ---- Final argmin across the 16 columns held by this quad's lanes ----
#pragma unroll
    for (int rt = 0; rt < 2; ++rt)
#pragma unroll
    for (int r = 0; r < 4; ++r) {
        float v = bestv[rt][r];
        int   idx = besti[rt][r];
#pragma unroll
        for (int m = 8; m >= 1; m >>= 1) {
            float ov = __shfl_xor(v, m, 64);
            int   oi = __shfl_xor(idx, m, 64);
            if (ov < v || (ov == v && oi < idx)) { v = ov; idx = oi; }
        }
        if (col == 0) {
            int q = wid * 32 + rt * 16 + qd * 4 + r;  // within block, 0..255
            fIdx[q] = idx;
            out[TOTAL_ELEMS + 1 + qbase + q] = (float)idx;
            atomicOr(&umask[idx >> 5], 1u << (idx & 31));  // LDS, cheap
        }
    }
    __syncthreads();

    // ---- Gather z_q, write coalesced, accumulate mse partial ----
    const int q  = tid & (QPB - 1);
    const int dh = tid >> 8;  // even/odd dims
    const int n  = qbase + q;
    const int bb = n >> 10;
    const int hw = n & (HW - 1);
    const int myIdx = fIdx[q];
    const float* erow = emb + myIdx * DIMS;
    float lsum = 0.f;
#pragma unroll
    for (int it = 0; it < 32; ++it) {
        int d = it * 2 + dh;
        float v = erow[d];                         // random row, L2/L3-resident
        int   o = bb * (DIMS * HW) + d * HW + hw;  // consecutive q -> coalesced
        float ze = z_e[o];
        out[o] = v;
        float df = ze - v;
        lsum = fmaf(df, df, lsum);
    }
#pragma unroll
    for (int off = 32; off > 0; off >>= 1) lsum += __shfl_down(lsum, off, 64);
    if (lane == 0) wsum[wid] = lsum;
    __syncthreads();

    // ---- Publish block results (device-scope) + last-block finalize ----
    if (tid < 32) atomicOr(&ws_flags[tid], umask[tid]);
    if (tid == 0) {
        float bsum = 0.f;
#pragma unroll
        for (int w = 0; w < 8; ++w) bsum += wsum[w];
        atomicAdd(ws_loss, bsum);
    }
    __threadfence();  // drain this block's atomics before taking the ticket
    if (tid == 0) lastBlk = (atomicAdd(ws_cnt, 1) == NBLK - 1) ? 1 : 0;
    __syncthreads();
    if (lastBlk) {
        int c = 0;
        if (tid < 32) c = __popc(atomicOr(&ws_flags[tid], 0u));  // coherent read
        if (tid < 64) {
#pragma unroll
            for (int off = 32; off >= 1; off >>= 1) c += __shfl_down(c, off, 64);
        }
        if (tid == 0) {
            float L = atomicAdd(ws_loss, 0.f);  // coherent read
            out[TOTAL_ELEMS] = L / (float)TOTAL_ELEMS;
            out[TOTAL_ELEMS + 1 + N_QUERIES] = (float)c / (float)K_CODES;
        }
    }
}

extern "C" void kernel_launch(void* const* d_in, const int* in_sizes, int n_in,
                              void* d_out, int out_size, void* d_ws, size_t ws_size,
                              hipStream_t stream) {
    const float* z_e = (const float*)d_in[0];
    const float* emb = (const float*)d_in[1];
    float* out = (float*)d_out;
    float*    ws_norm  = (float*)d_ws;
    unsigned* ws_flags = (unsigned*)((char*)d_ws + 4096);
    float*    ws_loss  = (float*)((char*)d_ws + 8192);
    int*      ws_cnt   = (int*)((char*)d_ws + 8256);

    vq_prep<<<4, 256, 0, stream>>>(emb, ws_norm, ws_flags, ws_loss, ws_cnt);
    vq_main<<<NBLK, 512, 0, stream>>>(z_e, emb, ws_norm, ws_flags, ws_loss,
                                      ws_cnt, out);
}